// Round 1
// baseline (3229.587 us; speedup 1.0000x reference)
//
#include <hip/hip_runtime.h>

// UAG_RNN: 4-direction spatial propagation RNN, fp32 (v1: correctness-first, VALU convs).
// B=8, C=64, H=128, W=128. 1x1 convs => per-position 64x64 channel matvecs.
// Stage 1: row scans (south/north), independent per (b,w): 2048 chains.
// Stage 2: col scans (se/sw/ne/nw), chained per (dir,b); H split into 8 bands of 16 rows
//          with boundary-row handoff via global slots + agent-scope acquire/release flags.

#define B_ 8
#define C_ 64
#define H_ 128
#define W_ 128
#define HW_ (H_*W_)      // 16384
#define CHW_ (C_*HW_)    // 1048576
#define TOT_ (B_*CHW_)   // 8388608
#define TW_ (C_*H_)      // 8192  (w-stride in transposed [b][w][c][h] layout)
#define SLOTS_N (4*8*8*128*64)   // dir x b x band x step x channel

__global__ void k_init(float* __restrict__ outT, int* __restrict__ flags) {
    int gid = blockIdx.x * 256 + threadIdx.x;
    for (int i = gid; i < TOT_; i += gridDim.x * 256) outT[i] = 0.f;
    if (gid < 256) flags[gid] = 0;
}

// y[b][c][h][w] -> yT[b][w][c][h]
__global__ void k_transpose_fwd(const float* __restrict__ in, float* __restrict__ outp) {
    __shared__ float t[32][33];
    int bid = blockIdx.x;
    int b = bid >> 10, c = (bid >> 4) & 63, ht = (bid >> 2) & 3, wt = bid & 3;
    int r = threadIdx.x >> 5, col = threadIdx.x & 31;
    const float* ip = in + (size_t)b * CHW_ + (size_t)c * HW_;
#pragma unroll
    for (int k = 0; k < 4; k++) {
        int rr = r + k * 8;
        t[rr][col] = ip[(ht * 32 + rr) * W_ + wt * 32 + col];   // t[h_local][w_local]
    }
    __syncthreads();
    float* op = outp + (size_t)b * CHW_ + c * 128;
#pragma unroll
    for (int k = 0; k < 4; k++) {
        int rr = r + k * 8;  // w_local
        op[(size_t)(wt * 32 + rr) * TW_ + ht * 32 + col] = t[col][rr];
    }
}

// outT[b][w][c][h] -> out[b][c][h][w]
__global__ void k_transpose_back(const float* __restrict__ inT, float* __restrict__ outp) {
    __shared__ float t[32][33];
    int bid = blockIdx.x;
    int b = bid >> 10, c = (bid >> 4) & 63, ht = (bid >> 2) & 3, wt = bid & 3;
    int r = threadIdx.x >> 5, col = threadIdx.x & 31;
    const float* ip = inT + (size_t)b * CHW_ + c * 128;
#pragma unroll
    for (int k = 0; k < 4; k++) {
        int rr = r + k * 8;  // w_local
        t[rr][col] = ip[(size_t)(wt * 32 + rr) * TW_ + ht * 32 + col];  // t[w_local][h_local]
    }
    __syncthreads();
    float* op = outp + (size_t)b * CHW_ + (size_t)c * HW_;
#pragma unroll
    for (int k = 0; k < 4; k++) {
        int rr = r + k * 8;  // h_local
        op[(ht * 32 + rr) * W_ + wt * 32 + col] = t[col][rr];
    }
}

// Row scans. grid 512 = scan(2) x b(8) x wband(32 of width 4). block 128 (2 waves).
// Each wave handles both convs (Wa, Wb rows in VGPRs) for 2 w-positions.
__global__ __launch_bounds__(128) void k_rowscan(
        const float* __restrict__ x, const float* __restrict__ y,
        const float* __restrict__ Wc, const float* __restrict__ bc,
        float* __restrict__ hsT, float* __restrict__ hnT) {
    int bid = blockIdx.x;
    int s  = bid >> 8;          // 0 = south, 1 = north
    int b  = (bid >> 5) & 7;
    int wb = bid & 31;
    int w0 = wb * 4;
    int tid = threadIdx.x;
    int wave = tid >> 6, o = tid & 63;
    int ka = s ? 8 : 0, kb = s ? 9 : 1;

    float wa[64], wbr[64];
    const float* War = Wc + (ka * 64 + o) * 64;
    const float* Wbr = Wc + (kb * 64 + o) * 64;
#pragma unroll
    for (int c = 0; c < 64; c++) { wa[c] = War[c]; wbr[c] = Wbr[c]; }
    float ba = bc[ka * 64 + o], bb = bc[kb * 64 + o];

    float* dT = (s ? hnT : hsT) + (size_t)b * CHW_;
    const float* xb = x + (size_t)b * CHW_;
    const float* yb = y + (size_t)b * CHW_;

    __shared__ float xt[64][4], yt[64][4], st[64][4];

    // init: h0 = x row0 (south: no relu; north: relu), stored at its true row.
    {
        int row0 = s ? 127 : 0;
        for (int idx = tid; idx < 256; idx += 128) {
            int c = idx >> 2, w = idx & 3;
            float v = xb[c * HW_ + row0 * W_ + w0 + w];
            if (s) v = fmaxf(v, 0.f);
            st[c][w] = v;
            dT[(size_t)(w0 + w) * TW_ + c * 128 + row0] = v;
        }
    }
    __syncthreads();

    for (int i = 1; i < 128; i++) {
        int row  = s ? 127 - i : i;
        int yrow = s ? 128 - i : i - 1;
        for (int idx = tid; idx < 256; idx += 128) {
            int c = idx >> 2, w = idx & 3;
            xt[c][w] = xb[c * HW_ + row * W_ + w0 + w];
            yt[c][w] = yb[c * HW_ + yrow * W_ + w0 + w];
        }
        __syncthreads();
        float a0 = 0.f, a1 = 0.f, p0 = 0.f, p1 = 0.f;
        int wq = wave * 2;
#pragma unroll
        for (int c = 0; c < 64; c++) {
            float2 xv = *(const float2*)&xt[c][wq];
            float2 sv = *(const float2*)&st[c][wq];
            a0 += wa[c] * xv.x; a1 += wa[c] * xv.y;
            p0 += wbr[c] * sv.x; p1 += wbr[c] * sv.y;
        }
        __syncthreads();
        float y0 = yt[o][wq], y1 = yt[o][wq + 1];
        float h0 = fmaxf(a0 + ba + (p0 + bb) * y0, 0.f);
        float h1 = fmaxf(a1 + ba + (p1 + bb) * y1, 0.f);
        st[o][wq] = h0; st[o][wq + 1] = h1;
        dT[(size_t)(w0 + wq) * TW_ + o * 128 + row] = h0;
        dT[(size_t)(w0 + wq + 1) * TW_ + o * 128 + row] = h1;
        __syncthreads();
    }
}

// Col scans. grid 256 = dir(4) x b(8) x band(8 of 16 rows). block 192 (3 waves).
// wave0: conv_a(base), wave1: conv_b(state), wave2: conv_t(shifted state incl. halo).
__global__ __launch_bounds__(192) void k_colscan(
        const float* __restrict__ yTp,
        const float* __restrict__ hsT, const float* __restrict__ hnT,
        const float* __restrict__ Wc, const float* __restrict__ bc,
        const float* __restrict__ gam,
        float* __restrict__ outT, float* __restrict__ slots, int* __restrict__ flags) {
    int bid = blockIdx.x;
    int d = bid >> 6, b = (bid >> 3) & 7, band = bid & 7;
    int r0 = band * 16;
    int tid = threadIdx.x;
    int wave = tid / 64, o = tid & 63;
    int down = (d < 2) ? 1 : 0;      // se/sw use shift_down; ne/nw use shift_up
    int flip = d & 1;                // sw/nw scan right->left
    const float* base = ((d < 2) ? hsT : hnT) + (size_t)b * CHW_;
    int kt, ka, kb;
    if (d == 0)      { kt = 2;  ka = 3;  kb = 4;  }
    else if (d == 1) { kt = 5;  ka = 6;  kb = 7;  }
    else if (d == 2) { kt = 10; ka = 11; kb = 12; }
    else             { kt = 13; ka = 14; kb = 15; }
    float g = gam[d];

    int myk = (wave == 0) ? ka : (wave == 1) ? kb : kt;
    float wreg[64];
    const float* Wr = Wc + (myk * 64 + o) * 64;
#pragma unroll
    for (int c = 0; c < 64; c++) wreg[c] = Wr[c];
    float bias = bc[myk * 64 + o];

    const float* yB = yTp + (size_t)b * CHW_;
    float* oB = outT + (size_t)b * CHW_;

    int chain = (d * 8 + b) * 8;
    int nb_band = down ? band - 1 : band + 1;
    int have_nb = down ? (band > 0) : (band < 7);
    int* nbflag = flags + chain + (have_nb ? nb_band : band);
    int* myflag = flags + chain + band;
    size_t slotbase_me = (size_t)(chain + band) * 128 * 64;
    size_t slotbase_nb = (size_t)(chain + (have_nb ? nb_band : band)) * 128 * 64;
    int ys = down ? r0 - 1 : r0;     // first y row held in yt (17 rows)
    int bd_r = down ? 15 : 0;        // boundary row published each step

    __shared__ float bt[64][20], st[64][20], sh[64][20], ytl[64][20], cb1[64][20], cb2[64][20];

    // ---- j = 0 : c0 = relu(base col)
    {
        int c0col = flip ? 127 : 0;
        for (int idx = tid; idx < 1024; idx += 192) {
            int c = idx >> 4, r = idx & 15;
            float v = fmaxf(base[(size_t)c0col * TW_ + c * 128 + r0 + r], 0.f);
            st[c][r] = v;
            unsafeAtomicAdd(&oB[(size_t)c0col * TW_ + c * 128 + r0 + r], v);
            if (r == bd_r) slots[slotbase_me + c] = v;
        }
        __syncthreads();
        if (tid == 0)
            __hip_atomic_store(myflag, 1, __ATOMIC_RELEASE, __HIP_MEMORY_SCOPE_AGENT);
    }

    auto conv16 = [&](const float (*IN)[20], float* acc) {
#pragma unroll
        for (int c = 0; c < 64; c++) {
            float4 q0 = *(const float4*)&IN[c][0];
            float4 q1 = *(const float4*)&IN[c][4];
            float4 q2 = *(const float4*)&IN[c][8];
            float4 q3 = *(const float4*)&IN[c][12];
            float wv = wreg[c];
            acc[0]  += wv * q0.x; acc[1]  += wv * q0.y; acc[2]  += wv * q0.z; acc[3]  += wv * q0.w;
            acc[4]  += wv * q1.x; acc[5]  += wv * q1.y; acc[6]  += wv * q1.z; acc[7]  += wv * q1.w;
            acc[8]  += wv * q2.x; acc[9]  += wv * q2.y; acc[10] += wv * q2.z; acc[11] += wv * q2.w;
            acc[12] += wv * q3.x; acc[13] += wv * q3.y; acc[14] += wv * q3.z; acc[15] += wv * q3.w;
        }
    };

    for (int j = 1; j < 128; j++) {
        int cj   = flip ? 127 - j : j;
        int ycol = flip ? 128 - j : j - 1;

        if (tid == 0 && have_nb) {
            while (__hip_atomic_load(nbflag, __ATOMIC_ACQUIRE, __HIP_MEMORY_SCOPE_AGENT) < j) {
                __builtin_amdgcn_s_sleep(8);
            }
        }
        __syncthreads();

        // ---- loads
        for (int idx = tid; idx < 1024; idx += 192) {
            int c = idx >> 4, r = idx & 15;
            bt[c][r] = base[(size_t)cj * TW_ + c * 128 + r0 + r];
        }
        for (int idx = tid; idx < 1088; idx += 192) {
            int c = idx / 17, t = idx % 17;
            int gr = ys + t;
            ytl[c][t] = (gr >= 0 && gr < 128) ? yB[(size_t)ycol * TW_ + c * 128 + gr] : 0.f;
        }
        const float* nbslot = slots + slotbase_nb + (size_t)(j - 1) * 64;
        for (int idx = tid; idx < 1024; idx += 192) {
            int c = idx >> 4, t = idx & 15;
            float v;
            if (down) v = (t == 0)  ? (have_nb ? nbslot[c] : 0.f) : st[c][t - 1];
            else      v = (t == 15) ? (have_nb ? nbslot[c] : 0.f) : st[c][t + 1];
            sh[c][t] = v;
        }
        __syncthreads();

        // ---- convs (one per wave)
        float acc[16];
#pragma unroll
        for (int r = 0; r < 16; r++) acc[r] = 0.f;
        if (wave == 0)      conv16(bt, acc);
        else if (wave == 1) conv16(st, acc);
        else                conv16(sh, acc);

        if (wave == 1) {
            float4 t0, t1, t2, t3;
            float yv[16];
#pragma unroll
            for (int r = 0; r < 16; r++) yv[r] = ytl[o][down ? r + 1 : r];
            t0.x=(acc[0]+bias)*yv[0];  t0.y=(acc[1]+bias)*yv[1];  t0.z=(acc[2]+bias)*yv[2];  t0.w=(acc[3]+bias)*yv[3];
            t1.x=(acc[4]+bias)*yv[4];  t1.y=(acc[5]+bias)*yv[5];  t1.z=(acc[6]+bias)*yv[6];  t1.w=(acc[7]+bias)*yv[7];
            t2.x=(acc[8]+bias)*yv[8];  t2.y=(acc[9]+bias)*yv[9];  t2.z=(acc[10]+bias)*yv[10]; t2.w=(acc[11]+bias)*yv[11];
            t3.x=(acc[12]+bias)*yv[12]; t3.y=(acc[13]+bias)*yv[13]; t3.z=(acc[14]+bias)*yv[14]; t3.w=(acc[15]+bias)*yv[15];
            *(float4*)&cb1[o][0] = t0; *(float4*)&cb1[o][4] = t1;
            *(float4*)&cb1[o][8] = t2; *(float4*)&cb1[o][12] = t3;
        } else if (wave == 2) {
            float4 t0, t1, t2, t3;
            float yv[16];
#pragma unroll
            for (int r = 0; r < 16; r++) yv[r] = ytl[o][down ? r : r + 1];
            t0.x=(acc[0]+bias)*yv[0];  t0.y=(acc[1]+bias)*yv[1];  t0.z=(acc[2]+bias)*yv[2];  t0.w=(acc[3]+bias)*yv[3];
            t1.x=(acc[4]+bias)*yv[4];  t1.y=(acc[5]+bias)*yv[5];  t1.z=(acc[6]+bias)*yv[6];  t1.w=(acc[7]+bias)*yv[7];
            t2.x=(acc[8]+bias)*yv[8];  t2.y=(acc[9]+bias)*yv[9];  t2.z=(acc[10]+bias)*yv[10]; t2.w=(acc[11]+bias)*yv[11];
            t3.x=(acc[12]+bias)*yv[12]; t3.y=(acc[13]+bias)*yv[13]; t3.z=(acc[14]+bias)*yv[14]; t3.w=(acc[15]+bias)*yv[15];
            *(float4*)&cb2[o][0] = t0; *(float4*)&cb2[o][4] = t1;
            *(float4*)&cb2[o][8] = t2; *(float4*)&cb2[o][12] = t3;
        }
        __syncthreads();

        // ---- finalize (wave0): h = relu(convA + ba + convB*y + g*shift(convT*y))
        if (wave == 0) {
            float4 c1a = *(const float4*)&cb1[o][0], c1b = *(const float4*)&cb1[o][4];
            float4 c1c = *(const float4*)&cb1[o][8], c1d = *(const float4*)&cb1[o][12];
            float4 c2a = *(const float4*)&cb2[o][0], c2b = *(const float4*)&cb2[o][4];
            float4 c2c = *(const float4*)&cb2[o][8], c2d = *(const float4*)&cb2[o][12];
            float v1[16] = {c1a.x,c1a.y,c1a.z,c1a.w, c1b.x,c1b.y,c1b.z,c1b.w,
                            c1c.x,c1c.y,c1c.z,c1c.w, c1d.x,c1d.y,c1d.z,c1d.w};
            float v2[16] = {c2a.x,c2a.y,c2a.z,c2a.w, c2b.x,c2b.y,c2b.z,c2b.w,
                            c2c.x,c2c.y,c2c.z,c2c.w, c2d.x,c2d.y,c2d.z,c2d.w};
            float hv[16];
#pragma unroll
            for (int r = 0; r < 16; r++) {
                int gr = r0 + r;
                float term = g * v2[r];
                if (down ? (gr == 0) : (gr == 127)) term = 0.f;
                float h = fmaxf(acc[r] + bias + v1[r] + term, 0.f);
                hv[r] = h;
                unsafeAtomicAdd(&oB[(size_t)cj * TW_ + o * 128 + gr], h);
            }
            *(float4*)&st[o][0]  = make_float4(hv[0], hv[1], hv[2], hv[3]);
            *(float4*)&st[o][4]  = make_float4(hv[4], hv[5], hv[6], hv[7]);
            *(float4*)&st[o][8]  = make_float4(hv[8], hv[9], hv[10], hv[11]);
            *(float4*)&st[o][12] = make_float4(hv[12], hv[13], hv[14], hv[15]);
            slots[slotbase_me + (size_t)j * 64 + o] = hv[bd_r];
        }
        __syncthreads();
        if (tid == 0)
            __hip_atomic_store(myflag, j + 1, __ATOMIC_RELEASE, __HIP_MEMORY_SCOPE_AGENT);
    }
}

extern "C" void kernel_launch(void* const* d_in, const int* in_sizes, int n_in,
                              void* d_out, int out_size, void* d_ws, size_t ws_size,
                              hipStream_t stream) {
    const float* x   = (const float*)d_in[0];
    const float* y   = (const float*)d_in[1];
    const float* Wc  = (const float*)d_in[2];
    const float* bc  = (const float*)d_in[3];
    const float* gam = (const float*)d_in[4];
    float* out = (float*)d_out;

    float* ws   = (float*)d_ws;
    float* yT   = ws;
    float* hsT  = ws + (size_t)TOT_;
    float* hnT  = ws + 2 * (size_t)TOT_;
    float* outT = ws + 3 * (size_t)TOT_;
    float* slots = ws + 4 * (size_t)TOT_;
    int*   flags = (int*)(ws + 4 * (size_t)TOT_ + (size_t)SLOTS_N);
    // total ws use: (4*8388608 + 2097152)*4 B + 1 KiB ~= 142.6 MB

    hipLaunchKernelGGL(k_init,           dim3(4096), dim3(256), 0, stream, outT, flags);
    hipLaunchKernelGGL(k_transpose_fwd,  dim3(8192), dim3(256), 0, stream, y, yT);
    hipLaunchKernelGGL(k_rowscan,        dim3(512),  dim3(128), 0, stream, x, y, Wc, bc, hsT, hnT);
    hipLaunchKernelGGL(k_colscan,        dim3(256),  dim3(192), 0, stream, yT, hsT, hnT, Wc, bc, gam,
                       outT, slots, flags);
    hipLaunchKernelGGL(k_transpose_back, dim3(8192), dim3(256), 0, stream, outT, out);
}

// Round 2
// 1138.445 us; speedup vs baseline: 2.8368x; 2.8368x over previous
//
#include <hip/hip_runtime.h>

// UAG_RNN v2: relaxed-atomic L3 handoff (no acquire/release cache flushes),
// per-direction output buffers (no global fp32 atomics), register prefetch.
// B=8, C=64, H=128, W=128.

#define B_ 8
#define C_ 64
#define H_ 128
#define W_ 128
#define HW_ (H_*W_)      // 16384
#define CHW_ (C_*HW_)    // 1048576
#define TOT_ (B_*CHW_)   // 8388608
#define TW_ (C_*H_)      // 8192  (w-stride in transposed [b][w][c][h] layout)
#define SLOTS_N (256*128*64)   // (chain,band) x step x channel = 2097152

__global__ void k_zero_flags(int* __restrict__ flags) {
    flags[threadIdx.x] = 0;
}

__global__ void k_zero_out(float* __restrict__ o) {
    int g = blockIdx.x * 256 + threadIdx.x;
    for (int i = g; i < TOT_; i += gridDim.x * 256) o[i] = 0.f;
}

// y[b][c][h][w] -> yT[b][w][c][h]
__global__ void k_transpose_fwd(const float* __restrict__ in, float* __restrict__ outp) {
    __shared__ float t[32][33];
    int bid = blockIdx.x;
    int b = bid >> 10, c = (bid >> 4) & 63, ht = (bid >> 2) & 3, wt = bid & 3;
    int r = threadIdx.x >> 5, col = threadIdx.x & 31;
    const float* ip = in + (size_t)b * CHW_ + (size_t)c * HW_;
#pragma unroll
    for (int k = 0; k < 4; k++) {
        int rr = r + k * 8;
        t[rr][col] = ip[(ht * 32 + rr) * W_ + wt * 32 + col];   // t[h_local][w_local]
    }
    __syncthreads();
    float* op = outp + (size_t)b * CHW_ + c * 128;
#pragma unroll
    for (int k = 0; k < 4; k++) {
        int rr = r + k * 8;  // w_local
        op[(size_t)(wt * 32 + rr) * TW_ + ht * 32 + col] = t[col][rr];
    }
}

// Sum up to 4 dir buffers [b][w][c][h] and transpose -> out[b][c][h][w]
__global__ void k_tb(const float* __restrict__ i0, const float* __restrict__ i1,
                     const float* __restrict__ i2, const float* __restrict__ i3,
                     int n4, float* __restrict__ outp) {
    __shared__ float t[32][33];
    int bid = blockIdx.x;
    int b = bid >> 10, c = (bid >> 4) & 63, ht = (bid >> 2) & 3, wt = bid & 3;
    int r = threadIdx.x >> 5, col = threadIdx.x & 31;
    size_t base = (size_t)b * CHW_ + c * 128;
#pragma unroll
    for (int k = 0; k < 4; k++) {
        int rr = r + k * 8;  // w_local
        size_t src = base + (size_t)(wt * 32 + rr) * TW_ + ht * 32 + col;
        float v = i0[src];
        if (n4) v += i1[src] + i2[src] + i3[src];
        t[rr][col] = v;   // t[w_local][h_local]
    }
    __syncthreads();
    float* op = outp + (size_t)b * CHW_ + (size_t)c * HW_;
#pragma unroll
    for (int k = 0; k < 4; k++) {
        int rr = r + k * 8;  // h_local
        op[(ht * 32 + rr) * W_ + wt * 32 + col] = t[col][rr];
    }
}

// Row scans. grid 256 = scan(2) x b(8) x wband(16 of width 8). block 256 (4 waves).
__global__ __launch_bounds__(256) void k_rowscan(
        const float* __restrict__ x, const float* __restrict__ y,
        const float* __restrict__ Wc, const float* __restrict__ bc,
        float* __restrict__ hsT, float* __restrict__ hnT) {
    int bid = blockIdx.x;
    int s  = bid >> 7;          // 0 = south, 1 = north
    int b  = (bid >> 4) & 7;
    int wb = bid & 15;
    int w0 = wb * 8;
    int tid = threadIdx.x;
    int wave = tid >> 6, o = tid & 63;
    int ka = s ? 8 : 0, kb = s ? 9 : 1;

    float wa[64], wbr[64];
    const float* War = Wc + (ka * 64 + o) * 64;
    const float* Wbr = Wc + (kb * 64 + o) * 64;
#pragma unroll
    for (int c = 0; c < 64; c++) { wa[c] = War[c]; wbr[c] = Wbr[c]; }
    float ba = bc[ka * 64 + o], bb = bc[kb * 64 + o];

    float* dT = (s ? hnT : hsT) + (size_t)b * CHW_;
    const float* xb = x + (size_t)b * CHW_;
    const float* yb = y + (size_t)b * CHW_;

    __shared__ float xt[64][8], yt[64][8], st[64][8];
    __shared__ float obuf[8][64][16];   // [w][c][row&15], flushed every 16 rows (32 KB)

    // init row: h0 = x row0 (south(no relu)=s0 dir uses relu0=false; north uses relu)
    int row0 = s ? 127 : 0;
    {
        int idx = tid;
#pragma unroll
        for (int k = 0; k < 2; k++, idx += 256) {
            int c = idx >> 3, w = idx & 7;
            float v = xb[c * HW_ + row0 * W_ + w0 + w];
            if (s) v = fmaxf(v, 0.f);
            st[c][w] = v;
            obuf[w][c][row0 & 15] = v;
        }
    }
    // prefetch i=1
    float xr[2], yr[2];
    {
        int row = s ? 126 : 1, yrow = s ? 127 : 0;
        int idx = tid;
#pragma unroll
        for (int k = 0; k < 2; k++, idx += 256) {
            int c = idx >> 3, w = idx & 7;
            xr[k] = xb[c * HW_ + row * W_ + w0 + w];
            yr[k] = yb[c * HW_ + yrow * W_ + w0 + w];
        }
    }
    __syncthreads();

    int wq = wave * 2;
    for (int i = 1; i < 128; i++) {
        int row = s ? 127 - i : i;
        // A: commit prefetched row to LDS
        {
            int idx = tid;
#pragma unroll
            for (int k = 0; k < 2; k++, idx += 256) {
                int c = idx >> 3, w = idx & 7;
                xt[c][w] = xr[k]; yt[c][w] = yr[k];
            }
        }
        __syncthreads();   // B1
        // prefetch i+1
        if (i < 127) {
            int rown = s ? 127 - (i + 1) : i + 1;
            int yrown = s ? 127 - i : i;
            int idx = tid;
#pragma unroll
            for (int k = 0; k < 2; k++, idx += 256) {
                int c = idx >> 3, w = idx & 7;
                xr[k] = xb[c * HW_ + rown * W_ + w0 + w];
                yr[k] = yb[c * HW_ + yrown * W_ + w0 + w];
            }
        }
        // conv: lane o computes out-channel o for columns wq, wq+1
        float a0 = 0.f, a1 = 0.f, p0 = 0.f, p1 = 0.f;
#pragma unroll
        for (int c = 0; c < 64; c++) {
            float2 xv = *(const float2*)&xt[c][wq];
            float2 sv = *(const float2*)&st[c][wq];
            a0 += wa[c] * xv.x; a1 += wa[c] * xv.y;
            p0 += wbr[c] * sv.x; p1 += wbr[c] * sv.y;
        }
        __syncthreads();   // B2 (st reads done before overwrite)
        float y0 = yt[o][wq], y1 = yt[o][wq + 1];
        float h0 = fmaxf(a0 + ba + (p0 + bb) * y0, 0.f);
        float h1 = fmaxf(a1 + ba + (p1 + bb) * y1, 0.f);
        st[o][wq] = h0; st[o][wq + 1] = h1;
        obuf[wq][o][row & 15] = h0; obuf[wq + 1][o][row & 15] = h1;
        __syncthreads();   // B3 (obuf/st complete)
        // flush a 16-row block with line-sized stores
        if (s ? ((row & 15) == 0) : ((row & 15) == 15)) {
            int rbase = row & ~15;
            int p = tid;
#pragma unroll
            for (int k = 0; k < 2; k++, p += 256) {
                int w = p >> 6, c = p & 63;
                float4 q0 = *(const float4*)&obuf[w][c][0];
                float4 q1 = *(const float4*)&obuf[w][c][4];
                float4 q2 = *(const float4*)&obuf[w][c][8];
                float4 q3 = *(const float4*)&obuf[w][c][12];
                float* dst = dT + (size_t)(w0 + w) * TW_ + c * 128 + rbase;
                *(float4*)&dst[0] = q0; *(float4*)&dst[4] = q1;
                *(float4*)&dst[8] = q2; *(float4*)&dst[12] = q3;
            }
        }
    }
}

// Col scans. grid 256 = dir(4) x b(8) x band(8 of 16 rows). block 192 (3 waves).
__global__ __launch_bounds__(192) void k_colscan(
        const float* __restrict__ yTp,
        const float* __restrict__ hsT, const float* __restrict__ hnT,
        const float* __restrict__ Wc, const float* __restrict__ bc,
        const float* __restrict__ gam,
        float* __restrict__ outroot, int use4,
        float* __restrict__ slots, int* __restrict__ flags) {
    int bid = blockIdx.x;
    int d = bid >> 6, b = (bid >> 3) & 7, band = bid & 7;
    int r0 = band * 16;
    int tid = threadIdx.x;
    int wave = tid / 64, o = tid & 63;
    int down = (d < 2) ? 1 : 0;      // se/sw: shift_down; ne/nw: shift_up
    int flip = d & 1;                // sw/nw scan right->left
    const float* base = ((d < 2) ? hsT : hnT) + (size_t)b * CHW_;
    int kt, ka, kb;
    if (d == 0)      { kt = 2;  ka = 3;  kb = 4;  }
    else if (d == 1) { kt = 5;  ka = 6;  kb = 7;  }
    else if (d == 2) { kt = 10; ka = 11; kb = 12; }
    else             { kt = 13; ka = 14; kb = 15; }
    float g = gam[d];

    int myk = (wave == 0) ? ka : (wave == 1) ? kb : kt;
    float wreg[64];
    const float* Wr = Wc + (myk * 64 + o) * 64;
#pragma unroll
    for (int c = 0; c < 64; c++) wreg[c] = Wr[c];
    float bias = bc[myk * 64 + o];

    const float* yB = yTp + (size_t)b * CHW_;
    float* oB = (use4 ? outroot + (size_t)d * TOT_ : outroot) + (size_t)b * CHW_;

    int chain = (d * 8 + b) * 8;
    int nb_band = down ? band - 1 : band + 1;
    int have_nb = down ? (band > 0) : (band < 7);
    int* nbflag = flags + chain + (have_nb ? nb_band : band);
    int* myflag = flags + chain + band;
    size_t slotme = (size_t)(chain + band) * 128 * 64;
    size_t slotnb = (size_t)(chain + (have_nb ? nb_band : band)) * 128 * 64;
    int ys = down ? r0 - 1 : r0;     // first y row held in ytl (17 rows)
    int bd_r = down ? 15 : 0;        // boundary row published each step
    int bd_t = down ? 0 : 15;        // halo target row inside sh

    __shared__ float bt[64][20], st[64][20], sh[64][20], ytl[64][20], cb1[64][20], cb2[64][20];

    // ---- j = 0 : c0 = relu(base col)
    int c0col = flip ? 127 : 0;
    for (int idx = tid; idx < 1024; idx += 192) {
        int c = idx >> 4, r = idx & 15;
        float v = fmaxf(base[(size_t)c0col * TW_ + c * 128 + r0 + r], 0.f);
        st[c][r] = v;
        if (use4) oB[(size_t)c0col * TW_ + c * 128 + r0 + r] = v;
        else      unsafeAtomicAdd(&oB[(size_t)c0col * TW_ + c * 128 + r0 + r], v);
    }
    if (wave == 0) {
        // wave0 publishes the boundary row + flag (relaxed L3 protocol)
        float v0 = fmaxf(base[(size_t)c0col * TW_ + o * 128 + r0 + bd_r], 0.f);
        __hip_atomic_store(&slots[slotme + o], v0, __ATOMIC_RELAXED, __HIP_MEMORY_SCOPE_AGENT);
        asm volatile("s_waitcnt vmcnt(0)" ::: "memory");
        if (o == 0)
            __hip_atomic_store(myflag, 1, __ATOMIC_RELAXED, __HIP_MEMORY_SCOPE_AGENT);
    }

    // prefetch registers for next column
    float pbt[6], pyt[6];
    auto prefetch = [&](int j) {
        int cj = flip ? 127 - j : j, ycol = flip ? 128 - j : j - 1;
#pragma unroll
        for (int k = 0; k < 6; k++) {
            int idx = tid + k * 192;
            if (idx < 1024) { int c = idx >> 4, r = idx & 15;
                pbt[k] = base[(size_t)cj * TW_ + c * 128 + r0 + r]; }
        }
#pragma unroll
        for (int k = 0; k < 6; k++) {
            int idx = tid + k * 192;
            if (idx < 1088) { int c = idx / 17, t = idx % 17; int gr = ys + t;
                pyt[k] = (gr >= 0 && gr < 128) ? yB[(size_t)ycol * TW_ + c * 128 + gr] : 0.f; }
        }
    };
    prefetch(1);
    __syncthreads();

    auto conv16 = [&](const float (*IN)[20], float* acc) {
#pragma unroll
        for (int c = 0; c < 64; c++) {
            float4 q0 = *(const float4*)&IN[c][0];
            float4 q1 = *(const float4*)&IN[c][4];
            float4 q2 = *(const float4*)&IN[c][8];
            float4 q3 = *(const float4*)&IN[c][12];
            float wv = wreg[c];
            acc[0]  += wv * q0.x; acc[1]  += wv * q0.y; acc[2]  += wv * q0.z; acc[3]  += wv * q0.w;
            acc[4]  += wv * q1.x; acc[5]  += wv * q1.y; acc[6]  += wv * q1.z; acc[7]  += wv * q1.w;
            acc[8]  += wv * q2.x; acc[9]  += wv * q2.y; acc[10] += wv * q2.z; acc[11] += wv * q2.w;
            acc[12] += wv * q3.x; acc[13] += wv * q3.y; acc[14] += wv * q3.z; acc[15] += wv * q3.w;
        }
    };

    for (int j = 1; j < 128; j++) {
        int cj = flip ? 127 - j : j;

        if (tid == 0 && have_nb) {
            while (__hip_atomic_load(nbflag, __ATOMIC_RELAXED, __HIP_MEMORY_SCOPE_AGENT) < j) {
                __builtin_amdgcn_s_sleep(1);
            }
        }
        __syncthreads();   // B1
        asm volatile("" ::: "memory");

        // ---- phase A: commit prefetched tiles, build sh (shifted state + halo)
#pragma unroll
        for (int k = 0; k < 6; k++) {
            int idx = tid + k * 192;
            if (idx < 1024) { int c = idx >> 4, r = idx & 15; bt[c][r] = pbt[k]; }
        }
#pragma unroll
        for (int k = 0; k < 6; k++) {
            int idx = tid + k * 192;
            if (idx < 1088) { int c = idx / 17, t = idx % 17; ytl[c][t] = pyt[k]; }
        }
        for (int idx = tid; idx < 960; idx += 192) {
            int c = idx / 15, tt = idx % 15;
            int t = down ? tt + 1 : tt;
            sh[c][t] = st[c][down ? tt : tt + 1];
        }
        if (wave == 0) {
            float hl = 0.f;
            if (have_nb)
                hl = __hip_atomic_load(&slots[slotnb + (size_t)(j - 1) * 64 + o],
                                       __ATOMIC_RELAXED, __HIP_MEMORY_SCOPE_AGENT);
            sh[o][bd_t] = hl;
        }
        __syncthreads();   // B2

        // ---- convs (one matvec-batch per wave)
        float acc[16];
#pragma unroll
        for (int r = 0; r < 16; r++) acc[r] = 0.f;
        if (wave == 0)      conv16(bt, acc);
        else if (wave == 1) conv16(st, acc);
        else                conv16(sh, acc);

        if (j < 127) prefetch(j + 1);

        if (wave == 1) {
#pragma unroll
            for (int r = 0; r < 16; r++)
                cb1[o][r] = (acc[r] + bias) * ytl[o][down ? r + 1 : r];
        } else if (wave == 2) {
#pragma unroll
            for (int r = 0; r < 16; r++)
                cb2[o][r] = (acc[r] + bias) * ytl[o][down ? r : r + 1];
        }
        __syncthreads();   // B3

        // ---- finalize (wave0): h = relu(convA + ba + convB*y + g*shift(convT*y))
        if (wave == 0) {
            float4 c1a = *(const float4*)&cb1[o][0], c1b = *(const float4*)&cb1[o][4];
            float4 c1c = *(const float4*)&cb1[o][8], c1d = *(const float4*)&cb1[o][12];
            float4 c2a = *(const float4*)&cb2[o][0], c2b = *(const float4*)&cb2[o][4];
            float4 c2c = *(const float4*)&cb2[o][8], c2d = *(const float4*)&cb2[o][12];
            float v1[16] = {c1a.x,c1a.y,c1a.z,c1a.w, c1b.x,c1b.y,c1b.z,c1b.w,
                            c1c.x,c1c.y,c1c.z,c1c.w, c1d.x,c1d.y,c1d.z,c1d.w};
            float v2[16] = {c2a.x,c2a.y,c2a.z,c2a.w, c2b.x,c2b.y,c2b.z,c2b.w,
                            c2c.x,c2c.y,c2c.z,c2c.w, c2d.x,c2d.y,c2d.z,c2d.w};
            float hv[16];
#pragma unroll
            for (int r = 0; r < 16; r++) {
                int gr = r0 + r;
                float term = g * v2[r];
                if (down ? (gr == 0) : (gr == 127)) term = 0.f;
                hv[r] = fmaxf(acc[r] + bias + v1[r] + term, 0.f);
            }
            *(float4*)&st[o][0]  = make_float4(hv[0], hv[1], hv[2], hv[3]);
            *(float4*)&st[o][4]  = make_float4(hv[4], hv[5], hv[6], hv[7]);
            *(float4*)&st[o][8]  = make_float4(hv[8], hv[9], hv[10], hv[11]);
            *(float4*)&st[o][12] = make_float4(hv[12], hv[13], hv[14], hv[15]);
            float* dst = &oB[(size_t)cj * TW_ + o * 128 + r0];
            if (use4) {
                *(float4*)&dst[0]  = make_float4(hv[0], hv[1], hv[2], hv[3]);
                *(float4*)&dst[4]  = make_float4(hv[4], hv[5], hv[6], hv[7]);
                *(float4*)&dst[8]  = make_float4(hv[8], hv[9], hv[10], hv[11]);
                *(float4*)&dst[12] = make_float4(hv[12], hv[13], hv[14], hv[15]);
            } else {
#pragma unroll
                for (int r = 0; r < 16; r++) unsafeAtomicAdd(&dst[r], hv[r]);
            }
            __hip_atomic_store(&slots[slotme + (size_t)j * 64 + o], hv[bd_r],
                               __ATOMIC_RELAXED, __HIP_MEMORY_SCOPE_AGENT);
            asm volatile("s_waitcnt vmcnt(0)" ::: "memory");
            if (o == 0)
                __hip_atomic_store(myflag, j + 1, __ATOMIC_RELAXED, __HIP_MEMORY_SCOPE_AGENT);
        }
        __syncthreads();   // B4
    }
}

extern "C" void kernel_launch(void* const* d_in, const int* in_sizes, int n_in,
                              void* d_out, int out_size, void* d_ws, size_t ws_size,
                              hipStream_t stream) {
    const float* x   = (const float*)d_in[0];
    const float* y   = (const float*)d_in[1];
    const float* Wc  = (const float*)d_in[2];
    const float* bc  = (const float*)d_in[3];
    const float* gam = (const float*)d_in[4];
    float* out = (float*)d_out;

    float* ws    = (float*)d_ws;
    float* yT    = ws;
    float* hsT   = ws + (size_t)TOT_;
    float* hnT   = ws + 2 * (size_t)TOT_;
    float* slots = ws + 3 * (size_t)TOT_;
    int*   flags = (int*)(slots + (size_t)SLOTS_N);
    float* outroot = (float*)(flags + 256);
    size_t need4 = ((size_t)7 * TOT_ + SLOTS_N + 256) * 4;   // ~243 MB
    int use4 = (ws_size >= need4) ? 1 : 0;

    hipLaunchKernelGGL(k_zero_flags, dim3(1), dim3(256), 0, stream, flags);
    if (!use4)
        hipLaunchKernelGGL(k_zero_out, dim3(4096), dim3(256), 0, stream, outroot);
    hipLaunchKernelGGL(k_transpose_fwd, dim3(8192), dim3(256), 0, stream, y, yT);
    hipLaunchKernelGGL(k_rowscan, dim3(256), dim3(256), 0, stream, x, y, Wc, bc, hsT, hnT);
    hipLaunchKernelGGL(k_colscan, dim3(256), dim3(192), 0, stream, yT, hsT, hnT, Wc, bc, gam,
                       outroot, use4, slots, flags);
    hipLaunchKernelGGL(k_tb, dim3(8192), dim3(256), 0, stream,
                       outroot,
                       use4 ? outroot + (size_t)TOT_     : outroot,
                       use4 ? outroot + 2 * (size_t)TOT_ : outroot,
                       use4 ? outroot + 3 * (size_t)TOT_ : outroot,
                       use4, out);
}

// Round 3
// 658.568 us; speedup vs baseline: 4.9040x; 1.7287x over previous
//
#include <hip/hip_runtime.h>

// UAG_RNN v3: MFMA recurrence steps (16x16x32 bf16, fp32 accum), NHWC layouts,
// relaxed-atomic L3 band handoff. B=8, C=64, H=128, W=128.

#define B_ 8
#define C_ 64
#define H_ 128
#define W_ 128
#define HW_ (H_*W_)      // 16384
#define CHW_ (C_*HW_)    // 1048576
#define TOT_ (B_*CHW_)   // 8388608
#define SLOTS_N (256*128*64)   // (chain,band) x step x channel = 2097152

typedef __attribute__((ext_vector_type(8))) short bfrag;
typedef __attribute__((ext_vector_type(4))) float f4_t;
typedef __attribute__((ext_vector_type(8))) unsigned short u16x8;

__device__ inline unsigned short bfr(float f) {
    unsigned int u = __float_as_uint(f);
    u += 0x7fffu + ((u >> 16) & 1u);
    return (unsigned short)(u >> 16);
}
__device__ inline bfrag packf(float4 a, float4 b) {
    bfrag r;
    r[0]=(short)bfr(a.x); r[1]=(short)bfr(a.y); r[2]=(short)bfr(a.z); r[3]=(short)bfr(a.w);
    r[4]=(short)bfr(b.x); r[5]=(short)bfr(b.y); r[6]=(short)bfr(b.z); r[7]=(short)bfr(b.w);
    return r;
}
__device__ inline ushort4 pack4(float a, float b, float c, float d) {
    ushort4 r; r.x=bfr(a); r.y=bfr(b); r.z=bfr(c); r.w=bfr(d); return r;
}

#define MFMA __builtin_amdgcn_mfma_f32_16x16x32_bf16

__global__ void k_zero_flags(int* __restrict__ flags) { flags[threadIdx.x] = 0; }

__global__ void k_zero_out(float* __restrict__ o, int n) {
    int g = blockIdx.x * 256 + threadIdx.x;
    for (int i = g; i < n; i += gridDim.x * 256) o[i] = 0.f;
}

// y[b][c][h*w] -> y2[b][h*w][c]   (NCHW -> NHWC)
__global__ void k_nhwc(const float* __restrict__ in, float* __restrict__ outp) {
    __shared__ float t[64][65];
    int blk = blockIdx.x;
    int b = blk >> 8, hw0 = (blk & 255) * 64;
    int cq = threadIdx.x >> 6, lo = threadIdx.x & 63;
    const float* ip = in + (size_t)b * CHW_;
#pragma unroll
    for (int p = 0; p < 16; p++) {
        int c = p * 4 + cq;
        t[c][lo] = ip[(size_t)c * HW_ + hw0 + lo];
    }
    __syncthreads();
    float* op = outp + (size_t)b * CHW_;
#pragma unroll
    for (int p = 0; p < 16; p++) {
        int hw = p * 4 + cq;
        op[(size_t)(hw0 + hw) * 64 + lo] = t[lo][hw];
    }
}

// sum cnt NHWC buffers -> out NCHW
__global__ void k_tb(const float* __restrict__ i0, const float* __restrict__ i1,
                     const float* __restrict__ i2, const float* __restrict__ i3,
                     int cnt, float* __restrict__ outp) {
    __shared__ float t[64][65];
    int blk = blockIdx.x;
    int b = blk >> 8, hw0 = (blk & 255) * 64;
    int cq = threadIdx.x >> 6, lo = threadIdx.x & 63;
    size_t bb = (size_t)b * CHW_;
#pragma unroll
    for (int p = 0; p < 16; p++) {
        int hw = p * 4 + cq;
        size_t s = bb + (size_t)(hw0 + hw) * 64 + lo;
        float v = i0[s] + i1[s];
        if (cnt == 4) v += i2[s] + i3[s];
        t[hw][lo] = v;
    }
    __syncthreads();
    float* op = outp + bb;
#pragma unroll
    for (int p = 0; p < 16; p++) {
        int c = p * 4 + cq;
        op[(size_t)c * HW_ + hw0 + lo] = t[lo][c];
    }
}

// Row scans: grid 256 = s(2) x b(8) x wb(16, width 8). ONE wave per block.
// h_i = relu(Wa*x_i + ba + (Wb*h_{i-1} + bb) * y_{i-1}), both convs via MFMA.
__global__ __launch_bounds__(64) void k_rowscan(
        const float* __restrict__ x, const float* __restrict__ y2,
        const float* __restrict__ Wc, const float* __restrict__ bc,
        float* __restrict__ hs2, float* __restrict__ hn2) {
    int bid = blockIdx.x;
    int s = bid >> 7, b = (bid >> 4) & 7, wb = bid & 15;
    int w0 = wb * 8;
    int lane = threadIdx.x, q = lane >> 4, n = lane & 15;
    int ka = s ? 8 : 0, kb = ka + 1;

    // weight A-fragments: A[m = mt*16 + n][k = kc*32 + q*8 + j]
    bfrag WaF[4][2], WbF[4][2];
#pragma unroll
    for (int mt = 0; mt < 4; mt++)
#pragma unroll
        for (int kc = 0; kc < 2; kc++) {
            const float* wp = Wc + (size_t)(ka * 64 + mt * 16 + n) * 64 + kc * 32 + q * 8;
            WaF[mt][kc] = packf(*(const float4*)wp, *(const float4*)(wp + 4));
            const float* wq = Wc + (size_t)(kb * 64 + mt * 16 + n) * 64 + kc * 32 + q * 8;
            WbF[mt][kc] = packf(*(const float4*)wq, *(const float4*)(wq + 4));
        }
    float4 baR[4], bbR[4];
#pragma unroll
    for (int mt = 0; mt < 4; mt++) {
        baR[mt] = *(const float4*)&bc[ka * 64 + mt * 16 + q * 4];
        bbR[mt] = *(const float4*)&bc[kb * 64 + mt * 16 + q * 4];
    }

    const float* xb = x + (size_t)b * CHW_;
    const float* yb = y2 + (size_t)b * CHW_;
    float* dT = (s ? hn2 : hs2) + (size_t)b * CHW_;

    __shared__ __align__(16) unsigned short st16[8][72];

    // init: h0 = x[row0] (north: relu)
    int row0 = s ? 127 : 0;
    {
        int w = lane >> 3, cg = lane & 7;
        float v[8];
#pragma unroll
        for (int j = 0; j < 8; j++) {
            float t = xb[(size_t)(cg * 8 + j) * HW_ + row0 * W_ + w0 + w];
            v[j] = s ? fmaxf(t, 0.f) : t;
        }
        u16x8 pk;
#pragma unroll
        for (int j = 0; j < 8; j++) pk[j] = bfr(v[j]);
        *(u16x8*)&st16[w][cg * 8] = pk;
        float* op = dT + (size_t)(row0 * 128 + w0 + w) * 64 + cg * 8;
        *(float4*)&op[0] = make_float4(v[0], v[1], v[2], v[3]);
        *(float4*)&op[4] = make_float4(v[4], v[5], v[6], v[7]);
    }

    // prefetch for i=1
    float xf[16]; float4 yv[4];
    {
        int row1 = s ? 126 : 1;
        int yrow1 = row0;
#pragma unroll
        for (int kc = 0; kc < 2; kc++)
#pragma unroll
            for (int j = 0; j < 8; j++) {
                int c = kc * 32 + q * 8 + j;
                xf[kc * 8 + j] = (n < 8) ? xb[(size_t)c * HW_ + row1 * W_ + w0 + n] : 0.f;
            }
        int wn = w0 + (n < 8 ? n : 7);
#pragma unroll
        for (int mt = 0; mt < 4; mt++)
            yv[mt] = *(const float4*)&yb[(size_t)(yrow1 * 128 + wn) * 64 + mt * 16 + q * 4];
    }
    __syncthreads();

    for (int i = 1; i < 128; i++) {
        int row = s ? 127 - i : i;
        __syncthreads();  // order prev st16 writes before reads (single wave: cheap)

        int rr = (n < 8) ? n : n - 8;
        bfrag fb0 = *(const bfrag*)&st16[rr][q * 8];
        bfrag fb1 = *(const bfrag*)&st16[rr][32 + q * 8];
        bfrag fa0, fa1;
#pragma unroll
        for (int j = 0; j < 8; j++) { fa0[j] = (short)bfr(xf[j]); fa1[j] = (short)bfr(xf[8 + j]); }

        f4_t Da[4], Db[4];
#pragma unroll
        for (int mt = 0; mt < 4; mt++) {
            f4_t z = {0.f, 0.f, 0.f, 0.f};
            Db[mt] = MFMA(WbF[mt][0], fb0, z, 0, 0, 0);
            Db[mt] = MFMA(WbF[mt][1], fb1, Db[mt], 0, 0, 0);
            Da[mt] = MFMA(WaF[mt][0], fa0, z, 0, 0, 0);
            Da[mt] = MFMA(WaF[mt][1], fa1, Da[mt], 0, 0, 0);
        }

        // prefetch i+1
        float xfN[16]; float4 yvN[4];
        if (i < 127) {
            int rowN = s ? 127 - (i + 1) : i + 1;
            int yrowN = s ? rowN + 1 : rowN - 1;
#pragma unroll
            for (int kc = 0; kc < 2; kc++)
#pragma unroll
                for (int j = 0; j < 8; j++) {
                    int c = kc * 32 + q * 8 + j;
                    xfN[kc * 8 + j] = (n < 8) ? xb[(size_t)c * HW_ + rowN * W_ + w0 + n] : 0.f;
                }
            int wn = w0 + (n < 8 ? n : 7);
#pragma unroll
            for (int mt = 0; mt < 4; mt++)
                yvN[mt] = *(const float4*)&yb[(size_t)(yrowN * 128 + wn) * 64 + mt * 16 + q * 4];
        }
        __syncthreads();  // readers done before overwrite

        if (n < 8) {
            float yA[4][4];
#pragma unroll
            for (int mt = 0; mt < 4; mt++) {
                yA[mt][0]=yv[mt].x; yA[mt][1]=yv[mt].y; yA[mt][2]=yv[mt].z; yA[mt][3]=yv[mt].w;
            }
#pragma unroll
            for (int mt = 0; mt < 4; mt++) {
                float ba4[4] = {baR[mt].x, baR[mt].y, baR[mt].z, baR[mt].w};
                float bb4[4] = {bbR[mt].x, bbR[mt].y, bbR[mt].z, bbR[mt].w};
                float h[4];
#pragma unroll
                for (int r = 0; r < 4; r++)
                    h[r] = fmaxf(Da[mt][r] + ba4[r] + (Db[mt][r] + bb4[r]) * yA[mt][r], 0.f);
                *(ushort4*)&st16[n][mt * 16 + q * 4] = pack4(h[0], h[1], h[2], h[3]);
                *(float4*)&dT[(size_t)(row * 128 + w0 + n) * 64 + mt * 16 + q * 4] =
                    make_float4(h[0], h[1], h[2], h[3]);
            }
        }
#pragma unroll
        for (int k = 0; k < 16; k++) xf[k] = xfN[k];
#pragma unroll
        for (int mt = 0; mt < 4; mt++) yv[mt] = yvN[mt];
    }
}

// Col scans: grid 256 = d(4) x b(8) x band(8 of 16 rows), 192 threads (3 waves).
// wave0: convA(base)+combine, wave1: convB(state), wave2: convT(shifted state).
__global__ __launch_bounds__(192) void k_colscan(
        const float* __restrict__ y2,
        const float* __restrict__ hs2, const float* __restrict__ hn2,
        const float* __restrict__ Wc, const float* __restrict__ bc,
        const float* __restrict__ gam,
        float* __restrict__ outD, int use4,
        float* __restrict__ slots, int* __restrict__ flags) {
    int bid = blockIdx.x;
    int d = bid >> 6, b = (bid >> 3) & 7, band = bid & 7;
    int r0 = band * 16;
    int tid = threadIdx.x;
    int wave = tid / 64, lane = tid & 63, q = lane >> 4, n = lane & 15;
    int down = (d < 2) ? 1 : 0;
    int flip = d & 1;
    const float* base = ((d < 2) ? hs2 : hn2) + (size_t)b * CHW_;
    int kt, ka, kb;
    if (d == 0)      { kt = 2;  ka = 3;  kb = 4;  }
    else if (d == 1) { kt = 5;  ka = 6;  kb = 7;  }
    else if (d == 2) { kt = 10; ka = 11; kb = 12; }
    else             { kt = 13; ka = 14; kb = 15; }
    float g = gam[d];
    int myk = (wave == 0) ? ka : (wave == 1) ? kb : kt;

    bfrag WF[4][2];
#pragma unroll
    for (int mt = 0; mt < 4; mt++)
#pragma unroll
        for (int kc = 0; kc < 2; kc++) {
            const float* wp = Wc + (size_t)(myk * 64 + mt * 16 + n) * 64 + kc * 32 + q * 8;
            WF[mt][kc] = packf(*(const float4*)wp, *(const float4*)(wp + 4));
        }
    float4 biF[4];
#pragma unroll
    for (int mt = 0; mt < 4; mt++)
        biF[mt] = *(const float4*)&bc[myk * 64 + mt * 16 + q * 4];

    const float* yB = y2 + (size_t)b * CHW_;
    float* oB = (use4 ? outD + (size_t)d * TOT_ : outD + (size_t)(d & 1) * TOT_) + (size_t)b * CHW_;

    int chain = (d * 8 + b) * 8;
    int nb_band = down ? band - 1 : band + 1;
    int have_nb = down ? (band > 0) : (band < 7);
    int* nbflag = flags + chain + (have_nb ? nb_band : band);
    int* myflag = flags + chain + band;
    size_t slotme = (size_t)(chain + band) * 128 * 64;
    size_t slotnb = (size_t)(chain + (have_nb ? nb_band : band)) * 128 * 64;
    int bd_r = down ? 15 : 0;    // boundary state row published each step
    int bd_t = down ? 0 : 15;    // lane-row whose convT B-frag comes from neighbor halo

    __shared__ __align__(16) unsigned short st16[16][72];
    __shared__ __align__(16) float cb1[4][64][4];
    __shared__ __align__(16) float cb2[4][64][4];

    // ---- j=0: c0 = relu(base col)
    int c0col = flip ? 127 : 0;
    if (tid < 128) {
        int r = tid >> 3, cg = tid & 7;
        const float* sp = base + (size_t)((r0 + r) * 128 + c0col) * 64 + cg * 8;
        float v[8];
#pragma unroll
        for (int j = 0; j < 8; j++) v[j] = fmaxf(sp[j], 0.f);
        u16x8 pk;
#pragma unroll
        for (int j = 0; j < 8; j++) pk[j] = bfr(v[j]);
        *(u16x8*)&st16[r][cg * 8] = pk;
        float* op = oB + (size_t)((r0 + r) * 128 + c0col) * 64 + cg * 8;
        if (use4) {
            *(float4*)&op[0] = make_float4(v[0], v[1], v[2], v[3]);
            *(float4*)&op[4] = make_float4(v[4], v[5], v[6], v[7]);
        } else {
#pragma unroll
            for (int j = 0; j < 8; j++) unsafeAtomicAdd(&op[j], v[j]);
        }
        if (r == bd_r) {
#pragma unroll
            for (int j = 0; j < 8; j++)
                __hip_atomic_store(&slots[slotme + cg * 8 + j], v[j],
                                   __ATOMIC_RELAXED, __HIP_MEMORY_SCOPE_AGENT);
        }
    }
    asm volatile("s_waitcnt vmcnt(0)" ::: "memory");
    __syncthreads();
    if (tid == 0)
        __hip_atomic_store(myflag, 1, __ATOMIC_RELAXED, __HIP_MEMORY_SCOPE_AGENT);

    // per-wave prefetch for j=1
    float4 pf[4];     // wave0: base fragments
    float4 ypf[4];    // wave1/2: gating y
    {
        int cj1 = flip ? 126 : 1, ycol1 = flip ? 127 : 0;
        if (wave == 0) {
#pragma unroll
            for (int kc = 0; kc < 2; kc++) {
                const float* sp = base + (size_t)((r0 + n) * 128 + cj1) * 64 + kc * 32 + q * 8;
                pf[kc * 2]     = *(const float4*)sp;
                pf[kc * 2 + 1] = *(const float4*)(sp + 4);
            }
        } else if (wave == 1) {
#pragma unroll
            for (int mt = 0; mt < 4; mt++)
                ypf[mt] = *(const float4*)&yB[(size_t)((r0 + n) * 128 + ycol1) * 64 + mt * 16 + q * 4];
        } else {
            int rsh = down ? r0 + n - 1 : r0 + n + 1;
            rsh = rsh < 0 ? 0 : (rsh > 127 ? 127 : rsh);
#pragma unroll
            for (int mt = 0; mt < 4; mt++)
                ypf[mt] = *(const float4*)&yB[(size_t)(rsh * 128 + ycol1) * 64 + mt * 16 + q * 4];
        }
    }

    for (int j = 1; j < 128; j++) {
        int cj = flip ? 127 - j : j;

        if (tid == 0 && have_nb) {
            while (__hip_atomic_load(nbflag, __ATOMIC_RELAXED, __HIP_MEMORY_SCOPE_AGENT) < j)
                __builtin_amdgcn_s_sleep(1);
        }
        __syncthreads();   // B1

        f4_t D[4];
        if (wave == 0) {
            bfrag a0 = packf(pf[0], pf[1]);
            bfrag a1 = packf(pf[2], pf[3]);
#pragma unroll
            for (int mt = 0; mt < 4; mt++) {
                f4_t z = {0.f, 0.f, 0.f, 0.f};
                D[mt] = MFMA(WF[mt][0], a0, z, 0, 0, 0);
                D[mt] = MFMA(WF[mt][1], a1, D[mt], 0, 0, 0);
            }
        } else if (wave == 1) {
            bfrag f0 = *(const bfrag*)&st16[n][q * 8];
            bfrag f1 = *(const bfrag*)&st16[n][32 + q * 8];
#pragma unroll
            for (int mt = 0; mt < 4; mt++) {
                f4_t z = {0.f, 0.f, 0.f, 0.f};
                D[mt] = MFMA(WF[mt][0], f0, z, 0, 0, 0);
                D[mt] = MFMA(WF[mt][1], f1, D[mt], 0, 0, 0);
            }
            float ya[4][4];
#pragma unroll
            for (int mt = 0; mt < 4; mt++) {
                ya[mt][0]=ypf[mt].x; ya[mt][1]=ypf[mt].y; ya[mt][2]=ypf[mt].z; ya[mt][3]=ypf[mt].w;
            }
#pragma unroll
            for (int mt = 0; mt < 4; mt++) {
                float bi4[4] = {biF[mt].x, biF[mt].y, biF[mt].z, biF[mt].w};
                float4 o4;
                o4.x = (D[mt][0] + bi4[0]) * ya[mt][0];
                o4.y = (D[mt][1] + bi4[1]) * ya[mt][1];
                o4.z = (D[mt][2] + bi4[2]) * ya[mt][2];
                o4.w = (D[mt][3] + bi4[3]) * ya[mt][3];
                *(float4*)&cb1[mt][lane][0] = o4;
            }
            if (j < 127) {
                int ycolN = flip ? 127 - j : j;
#pragma unroll
                for (int mt = 0; mt < 4; mt++)
                    ypf[mt] = *(const float4*)&yB[(size_t)((r0 + n) * 128 + ycolN) * 64 + mt * 16 + q * 4];
            }
        } else {
            bfrag f0, f1;
            if (n == bd_t) {
#pragma unroll
                for (int j8 = 0; j8 < 8; j8++) {
                    float v0 = 0.f, v1 = 0.f;
                    if (have_nb) {
                        v0 = __hip_atomic_load(&slots[slotnb + (size_t)(j - 1) * 64 + q * 8 + j8],
                                               __ATOMIC_RELAXED, __HIP_MEMORY_SCOPE_AGENT);
                        v1 = __hip_atomic_load(&slots[slotnb + (size_t)(j - 1) * 64 + 32 + q * 8 + j8],
                                               __ATOMIC_RELAXED, __HIP_MEMORY_SCOPE_AGENT);
                    }
                    f0[j8] = (short)bfr(v0); f1[j8] = (short)bfr(v1);
                }
            } else {
                int rr = down ? n - 1 : n + 1;
                f0 = *(const bfrag*)&st16[rr][q * 8];
                f1 = *(const bfrag*)&st16[rr][32 + q * 8];
            }
#pragma unroll
            for (int mt = 0; mt < 4; mt++) {
                f4_t z = {0.f, 0.f, 0.f, 0.f};
                D[mt] = MFMA(WF[mt][0], f0, z, 0, 0, 0);
                D[mt] = MFMA(WF[mt][1], f1, D[mt], 0, 0, 0);
            }
            float ya[4][4];
#pragma unroll
            for (int mt = 0; mt < 4; mt++) {
                ya[mt][0]=ypf[mt].x; ya[mt][1]=ypf[mt].y; ya[mt][2]=ypf[mt].z; ya[mt][3]=ypf[mt].w;
            }
#pragma unroll
            for (int mt = 0; mt < 4; mt++) {
                float bi4[4] = {biF[mt].x, biF[mt].y, biF[mt].z, biF[mt].w};
                float4 o4;
                o4.x = (D[mt][0] + bi4[0]) * ya[mt][0];
                o4.y = (D[mt][1] + bi4[1]) * ya[mt][1];
                o4.z = (D[mt][2] + bi4[2]) * ya[mt][2];
                o4.w = (D[mt][3] + bi4[3]) * ya[mt][3];
                *(float4*)&cb2[mt][lane][0] = o4;
            }
            if (j < 127) {
                int ycolN = flip ? 127 - j : j;
                int rsh = down ? r0 + n - 1 : r0 + n + 1;
                rsh = rsh < 0 ? 0 : (rsh > 127 ? 127 : rsh);
#pragma unroll
                for (int mt = 0; mt < 4; mt++)
                    ypf[mt] = *(const float4*)&yB[(size_t)(rsh * 128 + ycolN) * 64 + mt * 16 + q * 4];
            }
        }
        __syncthreads();   // B2

        if (wave == 0) {
            bool zrow = down ? ((r0 + n) == 0) : ((r0 + n) == 127);
            float hv[4][4];
#pragma unroll
            for (int mt = 0; mt < 4; mt++) {
                float4 c1 = *(const float4*)&cb1[mt][lane][0];
                float4 c2 = *(const float4*)&cb2[mt][lane][0];
                float bi4[4] = {biF[mt].x, biF[mt].y, biF[mt].z, biF[mt].w};
                float c14[4] = {c1.x, c1.y, c1.z, c1.w};
                float c24[4] = {c2.x, c2.y, c2.z, c2.w};
#pragma unroll
                for (int r = 0; r < 4; r++) {
                    float term = zrow ? 0.f : g * c24[r];
                    hv[mt][r] = fmaxf(D[mt][r] + bi4[r] + c14[r] + term, 0.f);
                }
                *(ushort4*)&st16[n][mt * 16 + q * 4] =
                    pack4(hv[mt][0], hv[mt][1], hv[mt][2], hv[mt][3]);
            }
            if (n == bd_r) {
#pragma unroll
                for (int mt = 0; mt < 4; mt++)
#pragma unroll
                    for (int r = 0; r < 4; r++)
                        __hip_atomic_store(&slots[slotme + (size_t)j * 64 + mt * 16 + q * 4 + r],
                                           hv[mt][r], __ATOMIC_RELAXED, __HIP_MEMORY_SCOPE_AGENT);
            }
            asm volatile("s_waitcnt vmcnt(0)" ::: "memory");
            if (lane == 0)
                __hip_atomic_store(myflag, j + 1, __ATOMIC_RELAXED, __HIP_MEMORY_SCOPE_AGENT);
            // prefetch base fragments for j+1
            if (j < 127) {
                int cjN = flip ? 127 - (j + 1) : j + 1;
#pragma unroll
                for (int kc = 0; kc < 2; kc++) {
                    const float* sp = base + (size_t)((r0 + n) * 128 + cjN) * 64 + kc * 32 + q * 8;
                    pf[kc * 2]     = *(const float4*)sp;
                    pf[kc * 2 + 1] = *(const float4*)(sp + 4);
                }
            }
            // output stores (after flag publish; completion only needed by kernel end)
            float* op = oB + (size_t)((r0 + n) * 128 + cj) * 64;
            if (use4) {
#pragma unroll
                for (int mt = 0; mt < 4; mt++)
                    *(float4*)&op[mt * 16 + q * 4] =
                        make_float4(hv[mt][0], hv[mt][1], hv[mt][2], hv[mt][3]);
            } else {
#pragma unroll
                for (int mt = 0; mt < 4; mt++)
#pragma unroll
                    for (int r = 0; r < 4; r++)
                        unsafeAtomicAdd(&op[mt * 16 + q * 4 + r], hv[mt][r]);
            }
        }
        __syncthreads();   // B3
    }
}

extern "C" void kernel_launch(void* const* d_in, const int* in_sizes, int n_in,
                              void* d_out, int out_size, void* d_ws, size_t ws_size,
                              hipStream_t stream) {
    const float* x   = (const float*)d_in[0];
    const float* y   = (const float*)d_in[1];
    const float* Wc  = (const float*)d_in[2];
    const float* bc  = (const float*)d_in[3];
    const float* gam = (const float*)d_in[4];
    float* out = (float*)d_out;

    float* ws    = (float*)d_ws;
    float* y2    = ws;
    float* hs2   = ws + (size_t)TOT_;
    float* hn2   = ws + 2 * (size_t)TOT_;
    float* slots = ws + 3 * (size_t)TOT_;
    int*   flags = (int*)(slots + (size_t)SLOTS_N);
    float* outD  = (float*)(flags + 256);
    size_t need4 = ((size_t)7 * TOT_ + SLOTS_N + 256) * 4;   // ~243 MB
    int use4 = (ws_size >= need4) ? 1 : 0;

    hipLaunchKernelGGL(k_zero_flags, dim3(1), dim3(256), 0, stream, flags);
    if (!use4)
        hipLaunchKernelGGL(k_zero_out, dim3(4096), dim3(256), 0, stream, outD, 2 * TOT_);
    hipLaunchKernelGGL(k_nhwc, dim3(2048), dim3(256), 0, stream, y, y2);
    hipLaunchKernelGGL(k_rowscan, dim3(256), dim3(64), 0, stream, x, y2, Wc, bc, hs2, hn2);
    hipLaunchKernelGGL(k_colscan, dim3(256), dim3(192), 0, stream, y2, hs2, hn2, Wc, bc, gam,
                       outD, use4, slots, flags);
    hipLaunchKernelGGL(k_tb, dim3(2048), dim3(256), 0, stream,
                       outD,
                       outD + (size_t)TOT_,
                       use4 ? outD + 2 * (size_t)TOT_ : outD,
                       use4 ? outD + 3 * (size_t)TOT_ : outD + (size_t)TOT_,
                       use4 ? 4 : 2, out);
}

// Round 4
// 602.628 us; speedup vs baseline: 5.3592x; 1.0928x over previous
//
#include <hip/hip_runtime.h>

// UAG_RNN v4: single-block-per-chain col scans (zero inter-block sync, LDS-only
// shift coupling), bf16 NHWC intermediates, MFMA 16x16x32 with bias-in-acc.
// B=8, C=64, H=128, W=128.

#define B_ 8
#define C_ 64
#define H_ 128
#define W_ 128
#define HW_ (H_*W_)      // 16384
#define CHW_ (C_*HW_)    // 1048576
#define TOT_ (B_*CHW_)   // 8388608

typedef __attribute__((ext_vector_type(8))) short bfrag;
typedef __attribute__((ext_vector_type(4))) float f4_t;

__device__ inline unsigned short bfr(float f) {
    unsigned int u = __float_as_uint(f);
    u += 0x7fffu + ((u >> 16) & 1u);
    return (unsigned short)(u >> 16);
}
__device__ inline float b2f(unsigned short u) {
    return __uint_as_float(((unsigned int)u) << 16);
}
__device__ inline bfrag packf(float4 a, float4 b) {
    bfrag r;
    r[0]=(short)bfr(a.x); r[1]=(short)bfr(a.y); r[2]=(short)bfr(a.z); r[3]=(short)bfr(a.w);
    r[4]=(short)bfr(b.x); r[5]=(short)bfr(b.y); r[6]=(short)bfr(b.z); r[7]=(short)bfr(b.w);
    return r;
}
__device__ inline ushort4 pack4(float a, float b, float c, float d) {
    ushort4 r; r.x=bfr(a); r.y=bfr(b); r.z=bfr(c); r.w=bfr(d); return r;
}
// relu on two packed bf16 in a u32
__device__ inline unsigned int relu2(unsigned int w) {
    unsigned int lo = (w & 0x8000u) ? 0u : (w & 0xffffu);
    unsigned int hi = (w & 0x80000000u) ? 0u : (w & 0xffff0000u);
    return lo | hi;
}
__device__ inline uint4 relu8(uint4 v) {
    v.x = relu2(v.x); v.y = relu2(v.y); v.z = relu2(v.z); v.w = relu2(v.w);
    return v;
}

#define MFMA __builtin_amdgcn_mfma_f32_16x16x32_bf16

// x NCHW fp32 -> x2 NHWC bf16 ; y NCHW fp32 -> y2 NHWC fp32
__global__ void k_prep(const float* __restrict__ x, const float* __restrict__ y,
                       float* __restrict__ y2, unsigned short* __restrict__ x2) {
    __shared__ float t[64][65];
    int blk = blockIdx.x;
    int isx = blk >> 11; blk &= 2047;
    int b = blk >> 8, hw0 = (blk & 255) * 64;
    int cq = threadIdx.x >> 6, lo = threadIdx.x & 63;
    const float* ip = (isx ? x : y) + (size_t)b * CHW_;
#pragma unroll
    for (int p = 0; p < 16; p++) {
        int c = p * 4 + cq;
        t[c][lo] = ip[(size_t)c * HW_ + hw0 + lo];
    }
    __syncthreads();
    if (isx) {
        unsigned short* op = x2 + (size_t)b * CHW_;
#pragma unroll
        for (int p = 0; p < 16; p++) {
            int hw = p * 4 + cq;
            op[(size_t)(hw0 + hw) * 64 + lo] = bfr(t[lo][hw]);
        }
    } else {
        float* op = y2 + (size_t)b * CHW_;
#pragma unroll
        for (int p = 0; p < 16; p++) {
            int hw = p * 4 + cq;
            op[(size_t)(hw0 + hw) * 64 + lo] = t[lo][hw];
        }
    }
}

// sum 4 fp32 NHWC dir buffers -> out NCHW fp32
__global__ void k_tb(const float* __restrict__ i0, const float* __restrict__ i1,
                     const float* __restrict__ i2, const float* __restrict__ i3,
                     float* __restrict__ outp) {
    __shared__ float t[64][65];
    int blk = blockIdx.x;
    int b = blk >> 8, hw0 = (blk & 255) * 64;
    int cq = threadIdx.x >> 6, lo = threadIdx.x & 63;
    size_t bb = (size_t)b * CHW_;
#pragma unroll
    for (int p = 0; p < 16; p++) {
        int hw = p * 4 + cq;
        size_t s = bb + (size_t)(hw0 + hw) * 64 + lo;
        t[hw][lo] = i0[s] + i1[s] + i2[s] + i3[s];
    }
    __syncthreads();
    float* op = outp + bb;
#pragma unroll
    for (int p = 0; p < 16; p++) {
        int c = p * 4 + cq;
        op[(size_t)c * HW_ + hw0 + lo] = t[lo][c];
    }
}

// Row scans: grid 128 = s(2) x b(8) x wb(8 of width 16). 1 wave/block.
// h_i = relu(Wa*x_i + ba + (Wb*h_{i-1} + bb) * y_{i-1})
__global__ __launch_bounds__(64) void k_rowscan(
        const unsigned short* __restrict__ x2, const float* __restrict__ y2,
        const float* __restrict__ Wc, const float* __restrict__ bc,
        unsigned short* __restrict__ hs2, unsigned short* __restrict__ hn2) {
    int bid = blockIdx.x;
    int s = bid >> 6, b = (bid >> 3) & 7, wb = bid & 7;
    int w0 = wb * 16;
    int lane = threadIdx.x, q = lane >> 4, n = lane & 15;
    int ka = s ? 8 : 0, kb = ka + 1;

    bfrag WaF[4][2], WbF[4][2];
#pragma unroll
    for (int mt = 0; mt < 4; mt++)
#pragma unroll
        for (int kc = 0; kc < 2; kc++) {
            const float* wp = Wc + (size_t)(ka * 64 + mt * 16 + n) * 64 + kc * 32 + q * 8;
            WaF[mt][kc] = packf(*(const float4*)wp, *(const float4*)(wp + 4));
            const float* wq2 = Wc + (size_t)(kb * 64 + mt * 16 + n) * 64 + kc * 32 + q * 8;
            WbF[mt][kc] = packf(*(const float4*)wq2, *(const float4*)(wq2 + 4));
        }
    float4 baR[4], bbR[4];
#pragma unroll
    for (int mt = 0; mt < 4; mt++) {
        baR[mt] = *(const float4*)&bc[ka * 64 + mt * 16 + q * 4];
        bbR[mt] = *(const float4*)&bc[kb * 64 + mt * 16 + q * 4];
    }

    const unsigned short* xb = x2 + (size_t)b * CHW_;
    const float* yb = y2 + (size_t)b * CHW_;
    unsigned short* dT = (s ? hn2 : hs2) + (size_t)b * CHW_;

    __shared__ __align__(16) unsigned short stt[2][16][72];

    // init row0: h0 = x[row0] (north: relu'd)
    int row0 = s ? 127 : 0;
    {
        const unsigned short* sp = xb + (size_t)(row0 * 128 + w0 + n) * 64 + q * 16;
        uint4 v0 = *(const uint4*)sp;
        uint4 v1 = *(const uint4*)(sp + 8);
        if (s) { v0 = relu8(v0); v1 = relu8(v1); }
        *(uint4*)&stt[0][n][q * 16] = v0;
        *(uint4*)&stt[0][n][q * 16 + 8] = v1;
        unsigned short* op = dT + (size_t)(row0 * 128 + w0 + n) * 64 + q * 16;
        *(uint4*)op = v0;
        *(uint4*)(op + 8) = v1;
    }

    // prefetch i=1
    uint4 xf0, xf1; float4 yv[4];
    {
        int row1 = s ? 126 : 1;
        const unsigned short* sp = xb + (size_t)(row1 * 128 + w0 + n) * 64 + q * 8;
        xf0 = *(const uint4*)sp;
        xf1 = *(const uint4*)(sp + 32);
#pragma unroll
        for (int mt = 0; mt < 4; mt++)
            yv[mt] = *(const float4*)&yb[(size_t)(row0 * 128 + w0 + n) * 64 + mt * 16 + q * 4];
    }
    __syncthreads();

    for (int i = 1; i < 128; i++) {
        int row = s ? 127 - i : i;
        int rd = (i - 1) & 1, wr = i & 1;

        bfrag fb0 = *(const bfrag*)&stt[rd][n][q * 8];
        bfrag fb1 = *(const bfrag*)&stt[rd][n][32 + q * 8];
        bfrag fa0 = *(const bfrag*)&xf0;
        bfrag fa1 = *(const bfrag*)&xf1;

        f4_t DA[4], DB[4];
#pragma unroll
        for (int mt = 0; mt < 4; mt++) {
            f4_t ca = {baR[mt].x, baR[mt].y, baR[mt].z, baR[mt].w};
            f4_t cb = {bbR[mt].x, bbR[mt].y, bbR[mt].z, bbR[mt].w};
            DA[mt] = MFMA(WaF[mt][0], fa0, ca, 0, 0, 0);
            DA[mt] = MFMA(WaF[mt][1], fa1, DA[mt], 0, 0, 0);
            DB[mt] = MFMA(WbF[mt][0], fb0, cb, 0, 0, 0);
            DB[mt] = MFMA(WbF[mt][1], fb1, DB[mt], 0, 0, 0);
        }

        uint4 xn0, xn1; float4 yn[4];
        if (i < 127) {
            int rowN = s ? 127 - (i + 1) : i + 1;
            int yrowN = s ? rowN + 1 : rowN - 1;
            const unsigned short* sp = xb + (size_t)(rowN * 128 + w0 + n) * 64 + q * 8;
            xn0 = *(const uint4*)sp;
            xn1 = *(const uint4*)(sp + 32);
#pragma unroll
            for (int mt = 0; mt < 4; mt++)
                yn[mt] = *(const float4*)&yb[(size_t)(yrowN * 128 + w0 + n) * 64 + mt * 16 + q * 4];
        }

#pragma unroll
        for (int mt = 0; mt < 4; mt++) {
            float h0 = fmaxf(DA[mt][0] + DB[mt][0] * yv[mt].x, 0.f);
            float h1 = fmaxf(DA[mt][1] + DB[mt][1] * yv[mt].y, 0.f);
            float h2 = fmaxf(DA[mt][2] + DB[mt][2] * yv[mt].z, 0.f);
            float h3 = fmaxf(DA[mt][3] + DB[mt][3] * yv[mt].w, 0.f);
            ushort4 pk = pack4(h0, h1, h2, h3);
            *(ushort4*)&stt[wr][n][mt * 16 + q * 4] = pk;
            *(ushort4*)&dT[(size_t)(row * 128 + w0 + n) * 64 + mt * 16 + q * 4] = pk;
        }
        if (i < 127) {
            xf0 = xn0; xf1 = xn1;
#pragma unroll
            for (int mt = 0; mt < 4; mt++) yv[mt] = yn[mt];
        }
        __syncthreads();
    }
}

// Col scans: grid 32 = d(4) x b(8). 512 threads = 8 waves; wave w owns rows
// [16w, 16w+16). Shift coupling entirely in LDS; 1 barrier/step (dbuf state).
__global__ __launch_bounds__(512, 2) void k_colscan(
        const float* __restrict__ y2,
        const unsigned short* __restrict__ hs2, const unsigned short* __restrict__ hn2,
        const float* __restrict__ Wc, const float* __restrict__ bc,
        const float* __restrict__ gam,
        float* __restrict__ outD) {
    int bid = blockIdx.x;
    int d = bid >> 3, b = bid & 7;
    int tid = threadIdx.x;
    int wave = tid >> 6, lane = tid & 63, q = lane >> 4, n = lane & 15;
    int row = wave * 16 + n;           // this lane's output row (N-dim)
    int down = (d < 2) ? 1 : 0;
    int flip = d & 1;
    const unsigned short* base2 = ((d < 2) ? hs2 : hn2) + (size_t)b * CHW_;
    int kt, ka, kb;
    if (d == 0)      { kt = 2;  ka = 3;  kb = 4;  }
    else if (d == 1) { kt = 5;  ka = 6;  kb = 7;  }
    else if (d == 2) { kt = 10; ka = 11; kb = 12; }
    else             { kt = 13; ka = 14; kb = 15; }
    float g = gam[d];

    bfrag WA[4][2], WB[4][2], WT[4][2];
#pragma unroll
    for (int mt = 0; mt < 4; mt++)
#pragma unroll
        for (int kc = 0; kc < 2; kc++) {
            const float* wa = Wc + (size_t)(ka * 64 + mt * 16 + n) * 64 + kc * 32 + q * 8;
            const float* wb = Wc + (size_t)(kb * 64 + mt * 16 + n) * 64 + kc * 32 + q * 8;
            const float* wt = Wc + (size_t)(kt * 64 + mt * 16 + n) * 64 + kc * 32 + q * 8;
            WA[mt][kc] = packf(*(const float4*)wa, *(const float4*)(wa + 4));
            WB[mt][kc] = packf(*(const float4*)wb, *(const float4*)(wb + 4));
            WT[mt][kc] = packf(*(const float4*)wt, *(const float4*)(wt + 4));
        }

    const float* yB = y2 + (size_t)b * CHW_;
    float* oB = outD + (size_t)d * TOT_ + (size_t)b * CHW_;

    __shared__ __align__(16) unsigned short stt[2][130][72];  // +1 zero pad each end
    __shared__ float biasL[3][64];
    if (tid < 192) {
        int which = tid >> 6, ch = tid & 63;
        int kk = (which == 0) ? ka : (which == 1) ? kb : kt;
        biasL[which][ch] = bc[kk * 64 + ch];
    }
    for (int idx = tid; idx < 2 * 2 * 72; idx += 512) {
        int buf = idx / 144, hi = (idx / 72) & 1, t = idx % 72;
        stt[buf][hi ? 129 : 0][t] = 0;
    }

    // ---- j = 0 : c0 = relu(base col0)
    int c0 = flip ? 127 : 0;
    {
        const unsigned short* sp = base2 + (size_t)(row * 128 + c0) * 64 + q * 16;
        uint4 v0 = relu8(*(const uint4*)sp);
        uint4 v1 = relu8(*(const uint4*)(sp + 8));
        *(uint4*)&stt[0][row + 1][q * 16] = v0;
        *(uint4*)&stt[0][row + 1][q * 16 + 8] = v1;
        float* op = oB + (size_t)(row * 128 + c0) * 64 + q * 16;
        unsigned int w8[8] = {v0.x, v0.y, v0.z, v0.w, v1.x, v1.y, v1.z, v1.w};
#pragma unroll
        for (int t = 0; t < 8; t++) {
            op[2 * t]     = b2f((unsigned short)(w8[t] & 0xffffu));
            op[2 * t + 1] = b2f((unsigned short)(w8[t] >> 16));
        }
    }

    int rsh = row + (down ? -1 : 1);
    rsh = rsh < 0 ? 0 : (rsh > 127 ? 127 : rsh);
    int srow = down ? row : row + 2;   // shifted-state LDS index (incl. +1 pad)
    float gT = (down ? (row == 0) : (row == 127)) ? 0.f : g;

    // prefetch j=1
    uint4 pb0, pb1; float4 yr[4], ys[4];
    {
        int cj1 = flip ? 126 : 1, yc1 = flip ? 127 : 0;
        const unsigned short* sp = base2 + (size_t)(row * 128 + cj1) * 64 + q * 8;
        pb0 = *(const uint4*)sp;
        pb1 = *(const uint4*)(sp + 32);
#pragma unroll
        for (int mt = 0; mt < 4; mt++) {
            yr[mt] = *(const float4*)&yB[(size_t)(row * 128 + yc1) * 64 + mt * 16 + q * 4];
            ys[mt] = *(const float4*)&yB[(size_t)(rsh * 128 + yc1) * 64 + mt * 16 + q * 4];
        }
    }
    __syncthreads();

    for (int j = 1; j < 128; j++) {
        int cj = flip ? 127 - j : j;
        int rd = (j - 1) & 1, wr = j & 1;

        // bias C-inits (LDS broadcast reads, loop-resident cheap)
        f4_t cA[4], cB[4], cT[4];
#pragma unroll
        for (int mt = 0; mt < 4; mt++) {
            float4 t0 = *(const float4*)&biasL[0][mt * 16 + q * 4];
            float4 t1 = *(const float4*)&biasL[1][mt * 16 + q * 4];
            float4 t2 = *(const float4*)&biasL[2][mt * 16 + q * 4];
            cA[mt] = f4_t{t0.x, t0.y, t0.z, t0.w};
            cB[mt] = f4_t{t1.x, t1.y, t1.z, t1.w};
            cT[mt] = f4_t{t2.x, t2.y, t2.z, t2.w};
        }

        bfrag fb0 = *(const bfrag*)&stt[rd][row + 1][q * 8];
        bfrag fb1 = *(const bfrag*)&stt[rd][row + 1][32 + q * 8];
        bfrag ft0 = *(const bfrag*)&stt[rd][srow][q * 8];
        bfrag ft1 = *(const bfrag*)&stt[rd][srow][32 + q * 8];
        bfrag fa0 = *(const bfrag*)&pb0;
        bfrag fa1 = *(const bfrag*)&pb1;

        f4_t DA[4], DB[4], DT[4];
#pragma unroll
        for (int mt = 0; mt < 4; mt++) {
            DA[mt] = MFMA(WA[mt][0], fa0, cA[mt], 0, 0, 0);
            DA[mt] = MFMA(WA[mt][1], fa1, DA[mt], 0, 0, 0);
            DB[mt] = MFMA(WB[mt][0], fb0, cB[mt], 0, 0, 0);
            DB[mt] = MFMA(WB[mt][1], fb1, DB[mt], 0, 0, 0);
            DT[mt] = MFMA(WT[mt][0], ft0, cT[mt], 0, 0, 0);
            DT[mt] = MFMA(WT[mt][1], ft1, DT[mt], 0, 0, 0);
        }

        // prefetch j+1
        uint4 nb0, nb1; float4 nyr[4], nys[4];
        if (j < 127) {
            int cjN = flip ? 127 - (j + 1) : j + 1;
            int ycN = flip ? 127 - j : j;
            const unsigned short* sp = base2 + (size_t)(row * 128 + cjN) * 64 + q * 8;
            nb0 = *(const uint4*)sp;
            nb1 = *(const uint4*)(sp + 32);
#pragma unroll
            for (int mt = 0; mt < 4; mt++) {
                nyr[mt] = *(const float4*)&yB[(size_t)(row * 128 + ycN) * 64 + mt * 16 + q * 4];
                nys[mt] = *(const float4*)&yB[(size_t)(rsh * 128 + ycN) * 64 + mt * 16 + q * 4];
            }
        }

        // finalize: h = relu(DA + DB*y_r + gT*DT*y_rsh)
#pragma unroll
        for (int mt = 0; mt < 4; mt++) {
            float yrv[4] = {yr[mt].x, yr[mt].y, yr[mt].z, yr[mt].w};
            float ysv[4] = {ys[mt].x, ys[mt].y, ys[mt].z, ys[mt].w};
            float h[4];
#pragma unroll
            for (int r = 0; r < 4; r++)
                h[r] = fmaxf(DA[mt][r] + DB[mt][r] * yrv[r] + gT * DT[mt][r] * ysv[r], 0.f);
            *(ushort4*)&stt[wr][row + 1][mt * 16 + q * 4] = pack4(h[0], h[1], h[2], h[3]);
            *(float4*)&oB[(size_t)(row * 128 + cj) * 64 + mt * 16 + q * 4] =
                make_float4(h[0], h[1], h[2], h[3]);
        }
        if (j < 127) {
            pb0 = nb0; pb1 = nb1;
#pragma unroll
            for (int mt = 0; mt < 4; mt++) { yr[mt] = nyr[mt]; ys[mt] = nys[mt]; }
        }
        __syncthreads();
    }
}

extern "C" void kernel_launch(void* const* d_in, const int* in_sizes, int n_in,
                              void* d_out, int out_size, void* d_ws, size_t ws_size,
                              hipStream_t stream) {
    const float* x   = (const float*)d_in[0];
    const float* y   = (const float*)d_in[1];
    const float* Wc  = (const float*)d_in[2];
    const float* bc  = (const float*)d_in[3];
    const float* gam = (const float*)d_in[4];
    float* out = (float*)d_out;

    // ws layout (bytes): x2 bf16 (16.8M), y2 fp32 (33.6M), hs2/hn2 bf16 (16.8M ea),
    // outD fp32 x4 dirs (134.2M) => ~218 MB total
    unsigned short* x2 = (unsigned short*)d_ws;
    float* y2 = (float*)d_ws + (size_t)TOT_ / 2;
    unsigned short* hs2 = (unsigned short*)(y2 + (size_t)TOT_);
    unsigned short* hn2 = hs2 + (size_t)TOT_;
    float* outD = (float*)(hn2 + (size_t)TOT_);

    hipLaunchKernelGGL(k_prep, dim3(4096), dim3(256), 0, stream, x, y, y2, x2);
    hipLaunchKernelGGL(k_rowscan, dim3(128), dim3(64), 0, stream, x2, y2, Wc, bc, hs2, hn2);
    hipLaunchKernelGGL(k_colscan, dim3(32), dim3(512), 0, stream, y2, hs2, hn2, Wc, bc, gam, outD);
    hipLaunchKernelGGL(k_tb, dim3(2048), dim3(256), 0, stream,
                       outD, outD + (size_t)TOT_, outD + 2 * (size_t)TOT_,
                       outD + 3 * (size_t)TOT_, out);
}